// Round 8
// baseline (255.270 us; speedup 1.0000x reference)
//
#include <hip/hip_runtime.h>
#include <hip/hip_bf16.h>

#define NB 64
#define CD 128
#define LL 4096
#define LCHUNK 64
#define NCHUNK 64      // LL/LCHUNK

typedef __attribute__((ext_vector_type(8))) short short8;
typedef __attribute__((ext_vector_type(4))) float f32x4;
typedef __attribute__((ext_vector_type(2))) unsigned u32x2;

#define LOG2E 1.4426950408889634f

// ws layout (bytes)
#define WT_OFF   0                                  // 3*128*128 bf16 = 96 KB
#define WSS_OFF  (1u<<20)                           // 2 MB
#define WSP_OFF  ((1u<<20) + NB*NCHUNK*CD*4)
#define POOL_OFF ((1u<<20) + 2u*NB*NCHUNK*CD*4)
#define WSQ_OFF  (8u<<20)                           // 64 MB bf16 sig(q), [n][d][l]

__device__ __forceinline__ unsigned short f2bf(float f) {
    union { float f; unsigned u; } v; v.f = f;
    unsigned r = v.u + 0x7FFFu + ((v.u >> 16) & 1u);
    return (unsigned short)(r >> 16);
}
__device__ __forceinline__ float bf2f(unsigned short h) {
    union { unsigned u; float f; } v; v.u = ((unsigned)h) << 16;
    return v.f;
}
__device__ __forceinline__ unsigned pack2(float lo, float hi) {
    union { __hip_bfloat162 h; unsigned u; } v;
    v.h = __float22bfloat162_rn(float2{lo, hi});   // v_cvt_pk_bf16_f32
    return v.u;
}

// W[t] is [C=128][D=128]; produce wt[t][d][c] = bf16(W[c][d])  (c contiguous)
__global__ void prep_wt(const float* __restrict__ Wq, const float* __restrict__ Wk,
                        const float* __restrict__ Wv, unsigned short* __restrict__ wt) {
    int t = blockIdx.x >> 7;
    int d = blockIdx.x & 127;
    const float* W = (t == 0) ? Wq : (t == 1) ? Wk : Wv;
    int c = threadIdx.x;
    wt[((size_t)t*CD + d)*CD + c] = f2bf(W[c*CD + d]);
}

// ---- pass 1: wave-independent fused QKV GEMM ----
// Each wave owns a 16-l slice: stages it, computes q,k,v for ALL 128 d,
// folds (s,p) per-lane, writes sig(q) bf16 to wsq. No barrier until tail.
// LDS per wave: 16 rows x 272 B; element (l,c): byte 272*l + 4*(c>>1) + 2*(c&1).
// A-frag (lane r,g): rows r, c = 32s+8g..+7 -> 16B at 272*r + 64*s + 16*g.
//   read bank-quad = (r + 4s + g) % 8 -> exactly 8 lanes each (uniform, min phases).
// acc[v] <-> (l_local = 4g+v, d = 16dg+r).
__global__ __launch_bounds__(256, 2)
void aft_qkv(const float* __restrict__ x, const unsigned short* __restrict__ wt,
             const float* __restrict__ bq, const float* __restrict__ bk,
             const float* __restrict__ bv,
             float* __restrict__ wsS, float* __restrict__ wsP,
             unsigned short* __restrict__ wsq) {
    __shared__ char lds_x[4 * 16 * 272];     // 17408 B: per-wave staging
    __shared__ float lds_red[2][4][CD];      // 4096 B: (s,p) per wave per d
    const int tid = threadIdx.x;
    const int n = blockIdx.x >> 6;
    const int ch = blockIdx.x & 63;
    const int ww = tid >> 6, lane = tid & 63, r = lane & 15, g = lane >> 4;
    const int l0 = ch * LCHUNK + ww * 16;    // this wave's 16-l slice
    char* my = lds_x + ww * (16 * 272);

    // ---- stage: lane owns c-pair (2*lane, 2*lane+1), 16 l each ----
    {
        const float* p0 = x + ((size_t)n*CD + 2*lane    )*LL + l0;
        const float* p1 = x + ((size_t)n*CD + 2*lane + 1)*LL + l0;
        f32x4 lo[4], hi[4];
#pragma unroll
        for (int j = 0; j < 4; ++j) { lo[j] = ((const f32x4*)p0)[j]; hi[j] = ((const f32x4*)p1)[j]; }
        char* b = my + 4*lane;
#pragma unroll
        for (int j = 0; j < 4; ++j)
#pragma unroll
            for (int jj = 0; jj < 4; ++jj)
                *(unsigned*)(b + (4*j + jj)*272) = pack2(lo[j][jj], hi[j][jj]);
    }

    // ---- A-fragments: read ONCE, reused by all 24 MFMA chains ----
    short8 a[4];
#pragma unroll
    for (int s = 0; s < 4; ++s)
        a[s] = *(const short8*)(my + 272*r + 64*s + 16*g);

    // ---- d-group loop: weights stream from L2, nothing carried across iterations ----
#pragma unroll 1
    for (int dg = 0; dg < 8; ++dg) {
        const int d = 16*dg + r;
        short8 wq[4], wk[4], wv[4];
#pragma unroll
        for (int s = 0; s < 4; ++s) {
            wq[s] = *(const short8*)(wt + ((size_t)(0*CD + d))*CD + 32*s + 8*g);
            wk[s] = *(const short8*)(wt + ((size_t)(1*CD + d))*CD + 32*s + 8*g);
            wv[s] = *(const short8*)(wt + ((size_t)(2*CD + d))*CD + 32*s + 8*g);
        }
        const float bql = bq[d], bkl = bk[d], bvl = bv[d];

        f32x4 aq = (f32x4){0,0,0,0};
        f32x4 ak = (f32x4){0,0,0,0};
        f32x4 av = (f32x4){0,0,0,0};
#pragma unroll
        for (int s = 0; s < 4; ++s) {
            aq = __builtin_amdgcn_mfma_f32_16x16x32_bf16(a[s], wq[s], aq, 0,0,0);
            ak = __builtin_amdgcn_mfma_f32_16x16x32_bf16(a[s], wk[s], ak, 0,0,0);
            av = __builtin_amdgcn_mfma_f32_16x16x32_bf16(a[s], wv[s], av, 0,0,0);
        }

        float s_dg = 0.f, p_dg = 0.f, sg[4];
#pragma unroll
        for (int v = 0; v < 4; ++v) {
            float e = __builtin_amdgcn_exp2f((ak[v] + bkl) * LOG2E);
            s_dg += e;
            p_dg += e * (av[v] + bvl);
            float q2 = (aq[v] + bql) * LOG2E;
            sg[v] = __builtin_amdgcn_rcpf(1.f + __builtin_amdgcn_exp2f(-q2));
        }
        // sig(q) -> wsq[n][d][l0 + 4g .. +3,+7] (8B per lane)
        u32x2 val = { pack2(sg[0], sg[1]), pack2(sg[2], sg[3]) };
        *(u32x2*)(wsq + ((size_t)n*CD + d)*LL + l0 + 4*g) = val;

        // fold (s,p) over the 4 g-lanes; g==0 lanes park per-wave partial in LDS
        s_dg += __shfl_xor(s_dg, 16, 64);  p_dg += __shfl_xor(p_dg, 16, 64);
        s_dg += __shfl_xor(s_dg, 32, 64);  p_dg += __shfl_xor(p_dg, 32, 64);
        if (g == 0) {
            lds_red[0][ww][d] = s_dg;
            lds_red[1][ww][d] = p_dg;
        }
    }

    // ---- tail: combine 4 waves -> per-chunk partial ----
    __syncthreads();
    if (tid < CD) {
        float s = 0.f, p = 0.f;
#pragma unroll
        for (int w2 = 0; w2 < 4; ++w2) { s += lds_red[0][w2][tid]; p += lds_red[1][w2][tid]; }
        size_t idx = ((size_t)n*NCHUNK + ch)*CD + tid;
        wsS[idx] = s;
        wsP[idx] = p;
    }
}

// ---------------- pass 2: combine partials -> pooled[n][d] ----------------
__global__ void aft_pass2(const float* __restrict__ wsS, const float* __restrict__ wsP,
                          float* __restrict__ pooled) {
    int n = blockIdx.x, d = threadIdx.x;
    float s = 0.f, p = 0.f;
    for (int b = 0; b < NCHUNK; ++b) {
        size_t idx = ((size_t)n*NCHUNK + b)*CD + d;
        s += wsS[idx];
        p += wsP[idx];
    }
    pooled[(size_t)n*CD + d] = p / s;
}

// ---- pass 3: out[n][d][l] = bf2f(wsq[n][d][l]) * pooled[n][d], pure streaming ----
__global__ __launch_bounds__(256)
void aft_pass3(const unsigned short* __restrict__ wsq, const float* __restrict__ pooled,
               float* __restrict__ out) {
    const int b = blockIdx.x;
    const int n = b >> 8;
    const int d = (b >> 1) & 127;
    const int half = b & 1;
    const float pl = pooled[(size_t)n*CD + d];
    const size_t base = ((size_t)n*CD + d)*LL + half*2048 + threadIdx.x*8;
    short8 v = *(const short8*)(wsq + base);
    f32x4 o0, o1;
#pragma unroll
    for (int j = 0; j < 4; ++j) {
        o0[j] = bf2f((unsigned short)v[j]) * pl;
        o1[j] = bf2f((unsigned short)v[4+j]) * pl;
    }
    *(f32x4*)(out + base) = o0;
    *(f32x4*)(out + base + 4) = o1;
}

extern "C" void kernel_launch(void* const* d_in, const int* in_sizes, int n_in,
                              void* d_out, int out_size, void* d_ws, size_t ws_size,
                              hipStream_t stream) {
    const float* x  = (const float*)d_in[0];
    const float* Wq = (const float*)d_in[1];
    const float* bq = (const float*)d_in[2];
    const float* Wk = (const float*)d_in[3];
    const float* bk = (const float*)d_in[4];
    const float* Wv = (const float*)d_in[5];
    const float* bv = (const float*)d_in[6];
    float* out = (float*)d_out;
    char* ws = (char*)d_ws;
    unsigned short* wt = (unsigned short*)(ws + WT_OFF);
    float* wsS = (float*)(ws + WSS_OFF);
    float* wsP = (float*)(ws + WSP_OFF);
    float* pooled = (float*)(ws + POOL_OFF);
    unsigned short* wsq = (unsigned short*)(ws + WSQ_OFF);

    prep_wt<<<384, 128, 0, stream>>>(Wq, Wk, Wv, wt);
    aft_qkv<<<NB * NCHUNK, 256, 0, stream>>>(x, wt, bq, bk, bv, wsS, wsP, wsq);
    aft_pass2<<<NB, CD, 0, stream>>>(wsS, wsP, pooled);
    aft_pass3<<<NB * CD * 2, 256, 0, stream>>>(wsq, pooled, out);
}

// Round 9
// 122.120 us; speedup vs baseline: 2.0903x; 2.0903x over previous
//
#include <hip/hip_runtime.h>
#include <hip/hip_bf16.h>

#define NB 64
#define CD 128
#define LL 4096
#define LCHUNK 64
#define NCHUNK 64      // LL/LCHUNK

typedef __attribute__((ext_vector_type(8))) short short8;
typedef __attribute__((ext_vector_type(4))) float f32x4;
typedef __attribute__((ext_vector_type(2))) unsigned u32x2;

#define LOG2E 1.4426950408889634f

// ws layout (bytes)
#define WT_OFF   0                                  // 3*128*128 bf16 = 96 KB
#define WSS_OFF  (1u<<20)                           // 2 MB
#define WSP_OFF  ((1u<<20) + NB*NCHUNK*CD*4)
#define POOL_OFF ((1u<<20) + 2u*NB*NCHUNK*CD*4)
#define WSQ_OFF  (8u<<20)                           // 64 MB bf16 sig(q), [n][d][l]

__device__ __forceinline__ unsigned short f2bf(float f) {
    union { float f; unsigned u; } v; v.f = f;
    unsigned r = v.u + 0x7FFFu + ((v.u >> 16) & 1u);
    return (unsigned short)(r >> 16);
}
__device__ __forceinline__ float bf2f(unsigned short h) {
    union { unsigned u; float f; } v; v.u = ((unsigned)h) << 16;
    return v.f;
}
__device__ __forceinline__ unsigned pack2(float lo, float hi) {
    union { __hip_bfloat162 h; unsigned u; } v;
    v.h = __float22bfloat162_rn(float2{lo, hi});   // v_cvt_pk_bf16_f32
    return v.u;
}

// W[t] is [C=128][D=128]; produce wt[t][d][c] = bf16(W[c][d])  (c contiguous)
__global__ void prep_wt(const float* __restrict__ Wq, const float* __restrict__ Wk,
                        const float* __restrict__ Wv, unsigned short* __restrict__ wt) {
    int t = blockIdx.x >> 7;
    int d = blockIdx.x & 127;
    const float* W = (t == 0) ? Wq : (t == 1) ? Wk : Wv;
    int c = threadIdx.x;
    wt[((size_t)t*CD + d)*CD + c] = f2bf(W[c*CD + d]);
}

// ---- pass 1: fused Q,K,V GEMM on one 64-l chunk; 8 waves x 16 d each ----
// LDS x: element (l,c) at byte 272*l + 16*((c>>3) ^ ((l>>2)&7)) + (c&7)*2
// A = x fragment (rows = l), B = wt row (cols = d). acc[v] <-> (l = l0+16lt+4g+v, d = 16ww+r)
__global__ __launch_bounds__(512, 2)
void aft_qkv(const float* __restrict__ x, const unsigned short* __restrict__ wt,
             const float* __restrict__ bq, const float* __restrict__ bk,
             const float* __restrict__ bv,
             float* __restrict__ wsS, float* __restrict__ wsP,
             unsigned short* __restrict__ wsq) {
    __shared__ char lds_x[64 * 272];
    const int tid = threadIdx.x;
    const int n = blockIdx.x >> 6;
    const int ch = blockIdx.x & 63;
    const int l0 = ch * LCHUNK;
    const int ww = tid >> 6, lane = tid & 63, r = lane & 15, g = lane >> 4;

    // ---- stage x[n][:, l0:l0+64] -> swizzled LDS bf16 (512 thr: 2 c-pairs each) ----
    {
        const int f = tid & 15, tg = tid >> 4;     // f: l-quad, tg: 0..31 c-pair group
#pragma unroll
        for (int it = 0; it < 2; ++it) {
            int cp = tg + 32*it;                   // c-pair 0..63
            f32x4 lo = *(const f32x4*)(x + ((size_t)n*CD + 2*cp    )*LL + l0 + 4*f);
            f32x4 hi = *(const f32x4*)(x + ((size_t)n*CD + 2*cp + 1)*LL + l0 + 4*f);
            char* base = lds_x + (4*f)*272 + 16*((cp >> 2) ^ (f & 7)) + 4*(cp & 3);
#pragma unroll
            for (int j = 0; j < 4; ++j)
                *(unsigned*)(base + j*272) = pack2(lo[j], hi[j]);
        }
    }

    // ---- B-fragments: lane holds wt[mat][d = 16ww + r][c = 32s+8g..+7] ----
    const int d = 16*ww + r;
    short8 b_q[4], b_k[4], b_v[4];
#pragma unroll
    for (int s = 0; s < 4; ++s) {
        b_q[s] = *(const short8*)(wt + ((size_t)(0*CD + d))*CD + 32*s + 8*g);
        b_k[s] = *(const short8*)(wt + ((size_t)(1*CD + d))*CD + 32*s + 8*g);
        b_v[s] = *(const short8*)(wt + ((size_t)(2*CD + d))*CD + 32*s + 8*g);
    }
    const float bql = bq[d], bkl = bk[d], bvl = bv[d];

    __syncthreads();

    float s_run = 0.f, p_run = 0.f;

#pragma unroll
    for (int lt = 0; lt < 4; ++lt) {
        // PIN: redefine weight fragments each iteration -> compiler cannot
        // rematerialize the global loads inside the loop; they stay in VGPRs.
#pragma unroll
        for (int s = 0; s < 4; ++s) {
            asm volatile("" : "+v"(b_q[s]));
            asm volatile("" : "+v"(b_k[s]));
            asm volatile("" : "+v"(b_v[s]));
        }
        const int lrow = 16*lt + r;
        const int lsw = (lrow >> 2) & 7;
        short8 a[4];
#pragma unroll
        for (int s = 0; s < 4; ++s)
            a[s] = *(const short8*)(lds_x + lrow*272 + 16*((4*s + g) ^ lsw));
        f32x4 aq = (f32x4){0,0,0,0};
        f32x4 ak = (f32x4){0,0,0,0};
        f32x4 av = (f32x4){0,0,0,0};
#pragma unroll
        for (int s = 0; s < 4; ++s) {
            aq = __builtin_amdgcn_mfma_f32_16x16x32_bf16(a[s], b_q[s], aq, 0,0,0);
            ak = __builtin_amdgcn_mfma_f32_16x16x32_bf16(a[s], b_k[s], ak, 0,0,0);
            av = __builtin_amdgcn_mfma_f32_16x16x32_bf16(a[s], b_v[s], av, 0,0,0);
        }
        float sg[4];
#pragma unroll
        for (int v = 0; v < 4; ++v) {
            float e = __builtin_amdgcn_exp2f((ak[v] + bkl) * LOG2E);
            s_run += e;
            p_run += e * (av[v] + bvl);
            float q2 = (aq[v] + bql) * LOG2E;
            sg[v] = __builtin_amdgcn_rcpf(1.f + __builtin_amdgcn_exp2f(-q2));
        }
        u32x2 val = { pack2(sg[0], sg[1]), pack2(sg[2], sg[3]) };
        // 8B store at (d, l = l0+16lt+4g); lt x g covers the full 64-l chunk
        *(u32x2*)(wsq + ((size_t)n*CD + d)*LL + l0 + 16*lt + 4*g) = val;
    }

    // ---- reduce (s,p) over the 4 g-lanes; lane g==0 writes d ----
    s_run += __shfl_xor(s_run, 16, 64);  p_run += __shfl_xor(p_run, 16, 64);
    s_run += __shfl_xor(s_run, 32, 64);  p_run += __shfl_xor(p_run, 32, 64);
    if (g == 0) {
        size_t idx = ((size_t)n*NCHUNK + ch)*CD + d;
        wsS[idx] = s_run;
        wsP[idx] = p_run;
    }
}

// ---------------- pass 2: combine partials -> pooled[n][d] ----------------
__global__ void aft_pass2(const float* __restrict__ wsS, const float* __restrict__ wsP,
                          float* __restrict__ pooled) {
    int n = blockIdx.x, d = threadIdx.x;
    float s = 0.f, p = 0.f;
    for (int b = 0; b < NCHUNK; ++b) {
        size_t idx = ((size_t)n*NCHUNK + b)*CD + d;
        s += wsS[idx];
        p += wsP[idx];
    }
    pooled[(size_t)n*CD + d] = p / s;
}

// ---- pass 3: out[n][d][l] = bf2f(wsq[n][d][l]) * pooled[n][d], pure streaming ----
__global__ __launch_bounds__(256)
void aft_pass3(const unsigned short* __restrict__ wsq, const float* __restrict__ pooled,
               float* __restrict__ out) {
    const int b = blockIdx.x;
    const int n = b >> 8;
    const int d = (b >> 1) & 127;
    const int half = b & 1;
    const float pl = pooled[(size_t)n*CD + d];
    const size_t base = ((size_t)n*CD + d)*LL + half*2048 + threadIdx.x*8;
    short8 v = *(const short8*)(wsq + base);
    f32x4 o0, o1;
#pragma unroll
    for (int j = 0; j < 4; ++j) {
        o0[j] = bf2f((unsigned short)v[j]) * pl;
        o1[j] = bf2f((unsigned short)v[4+j]) * pl;
    }
    *(f32x4*)(out + base) = o0;
    *(f32x4*)(out + base + 4) = o1;
}

extern "C" void kernel_launch(void* const* d_in, const int* in_sizes, int n_in,
                              void* d_out, int out_size, void* d_ws, size_t ws_size,
                              hipStream_t stream) {
    const float* x  = (const float*)d_in[0];
    const float* Wq = (const float*)d_in[1];
    const float* bq = (const float*)d_in[2];
    const float* Wk = (const float*)d_in[3];
    const float* bk = (const float*)d_in[4];
    const float* Wv = (const float*)d_in[5];
    const float* bv = (const float*)d_in[6];
    float* out = (float*)d_out;
    char* ws = (char*)d_ws;
    unsigned short* wt = (unsigned short*)(ws + WT_OFF);
    float* wsS = (float*)(ws + WSS_OFF);
    float* wsP = (float*)(ws + WSP_OFF);
    float* pooled = (float*)(ws + POOL_OFF);
    unsigned short* wsq = (unsigned short*)(ws + WSQ_OFF);

    prep_wt<<<384, 128, 0, stream>>>(Wq, Wk, Wv, wt);
    aft_qkv<<<NB * NCHUNK, 512, 0, stream>>>(x, wt, bq, bk, bv, wsS, wsP, wsq);
    aft_pass2<<<NB, CD, 0, stream>>>(wsS, wsP, pooled);
    aft_pass3<<<NB * CD * 2, 256, 0, stream>>>(wsq, pooled, out);
}